// Round 1
// baseline (711.610 us; speedup 1.0000x reference)
//
#include <hip/hip_runtime.h>

// PrRoIPool2D forward for MI355X.
// B=8, C=256, H=W=48, R=300, pooled 7x7, spatial_scale=1/16.
// out[r,c,ph,pw] = (1/area) * sum_j sum_i Wy[r,ph,j] * Wx[r,pw,i] * feat[b,c,j,i]
// Hat-integral weights have compact support (<=5 taps/axis for these ROI sizes).

#define PH 7
#define PW 7
#define SCALE 0.0625f
#define CH 256
#define FH 48
#define FW 48
#define RNUM 300

__device__ __forceinline__ float hat_int(float x, float g) {
    // integral_{-inf}^{x} of unit hat centered at g (support [g-1,g+1])
    float t = x - (g - 1.0f);
    if (t <= 0.0f) return 0.0f;
    if (t <= 1.0f) return 0.5f * t * t;
    if (t <= 2.0f) { float u = 2.0f - t; return 1.0f - 0.5f * u * u; }
    return 1.0f;
}

__global__ __launch_bounds__(256)
void prroi_pool_kernel(const float* __restrict__ feat,
                       const float* __restrict__ rois,
                       float* __restrict__ out) {
    const int bin = blockIdx.x;   // 0..48  (ph*7+pw)
    const int r   = blockIdx.y;   // 0..299
    const int ph  = bin / PW;
    const int pw  = bin % PW;
    const int c   = threadIdx.x;  // 0..255 channel

    // ROI params (uniform across block -> scalar loads / broadcast)
    const float* roi = rois + r * 5;
    const int   b  = (int)roi[0];
    const float x1 = roi[1] * SCALE;
    const float y1 = roi[2] * SCALE;
    const float x2 = roi[3] * SCALE;
    const float y2 = roi[4] * SCALE;

    const float roi_w = fmaxf(x2 - x1, 0.0f);
    const float roi_h = fmaxf(y2 - y1, 0.0f);
    const float bin_w = roi_w / (float)PW;
    const float bin_h = roi_h / (float)PH;

    const float xa = x1 + pw * bin_w;
    const float xb = xa + bin_w;
    const float ya = y1 + ph * bin_h;
    const float yb = ya + bin_h;
    const float area = bin_w * bin_h;

    // support bounds (weights outside are exactly 0; clamp to grid)
    const int i0 = max(0, (int)floorf(xa) - 1);
    const int i1 = min(FW - 1, (int)floorf(xb) + 1);
    const int j0 = max(0, (int)floorf(ya) - 1);
    const int j1 = min(FH - 1, (int)floorf(yb) + 1);

    // x-axis weights hoisted into registers (<=8 taps, unrolled)
    float wx[8];
#pragma unroll
    for (int k = 0; k < 8; ++k) {
        int i = i0 + k;
        wx[k] = (i <= i1) ? (hat_int(xb, (float)i) - hat_int(xa, (float)i)) : 0.0f;
    }

    const float* fbase = feat + ((size_t)(b * CH + c)) * (FH * FW);

    float acc = 0.0f;
    for (int j = j0; j <= j1; ++j) {
        const float wy = hat_int(yb, (float)j) - hat_int(ya, (float)j);
        const float* frow = fbase + j * FW;
        float rowsum = 0.0f;
#pragma unroll
        for (int k = 0; k < 8; ++k) {
            int i = i0 + k;
            if (i <= i1) rowsum += wx[k] * frow[i];
        }
        acc += wy * rowsum;
    }

    const float val = (area > 0.0f) ? (acc / area) : 0.0f;
    out[(((size_t)r * CH + c) * PH + ph) * PW + pw] = val;
}

extern "C" void kernel_launch(void* const* d_in, const int* in_sizes, int n_in,
                              void* d_out, int out_size, void* d_ws, size_t ws_size,
                              hipStream_t stream) {
    const float* feat = (const float*)d_in[0];
    const float* rois = (const float*)d_in[1];
    float* out = (float*)d_out;

    dim3 grid(PH * PW, RNUM);
    dim3 block(CH);
    prroi_pool_kernel<<<grid, block, 0, stream>>>(feat, rois, out);
}

// Round 2
// 182.091 us; speedup vs baseline: 3.9080x; 3.9080x over previous
//
#include <hip/hip_runtime.h>

// PrRoIPool2D forward, MI355X. B=8, C=256, H=W=48, R=300, 7x7 bins, scale=1/16.
// R1: transpose features to [B,H,W,C] in d_ws so channel gathers coalesce;
//     pool kernel stages per-(roi, channel-half) output in LDS and writes it
//     as one dense contiguous burst.

#define PH 7
#define PW 7
#define NBINS 49
#define SCALE 0.0625f
#define CH 256
#define FH 48
#define FW 48
#define RNUM 300
#define BATCH 8

__device__ __forceinline__ float hat_int(float x, float g) {
    float t = x - (g - 1.0f);
    if (t <= 0.0f) return 0.0f;
    if (t <= 1.0f) return 0.5f * t * t;
    if (t <= 2.0f) { float u = 2.0f - t; return 1.0f - 0.5f * u * u; }
    return 1.0f;
}

// ---- Kernel 1: [B,C,H,W] -> [B,H,W,C] -----------------------------------
// One block per (b,h) spatial row: reads 256 segments of 192 B (3 full lines
// each), writes one contiguous 48 KB burst. LDS padded to 49 floats/row:
// stride 49 = 17 mod 32 -> conflict-free on the c-fast read-back.
__global__ __launch_bounds__(256)
void transpose_bchw_bhwc(const float* __restrict__ in, float* __restrict__ outT) {
    const int bh = blockIdx.x;          // 0..383
    const int b  = bh / FH;
    const int h  = bh % FH;
    __shared__ float sm[CH * (FW + 1)];

    const float* src = in + (size_t)b * CH * FH * FW + (size_t)h * FW;
    // load in input order: idx over (c,w), w fast
    for (int idx = threadIdx.x; idx < CH * FW; idx += 256) {
        const int c = idx / FW;
        const int w = idx - c * FW;
        sm[c * (FW + 1) + w] = src[(size_t)c * FH * FW + w];
    }
    __syncthreads();
    // store in output order: idx over (w,c), c fast -> contiguous
    float* dst = outT + (size_t)bh * FW * CH;
    for (int idx = threadIdx.x; idx < CH * FW; idx += 256) {
        const int w = idx >> 8;          // 256 c per w
        const int c = idx & 255;
        dst[idx] = sm[c * (FW + 1) + w];
    }
}

// ---- Kernel 2: pooling ---------------------------------------------------
// grid (2, 300): blockIdx.x = channel half (128 ch), blockIdx.y = roi.
// 256 threads: lane c2 = tid&63 -> channel pair (float2), bq = tid>>6 ->
// bin = kb*4+bq (wave-uniform, so tap-count branches don't diverge).
// Output staged in LDS [128][49], then one contiguous float4 burst.
__global__ __launch_bounds__(256)
void prroi_pool_kernel(const float* __restrict__ featT,
                       const float* __restrict__ rois,
                       float* __restrict__ out) {
    const int cg = blockIdx.x;          // 0,1
    const int r  = blockIdx.y;          // 0..299
    const int cbase = cg * 128;
    const int c2 = threadIdx.x & 63;    // channel pair index
    const int bq = threadIdx.x >> 6;    // 0..3

    __shared__ float sm[128 * NBINS];   // 25088 B

    const float* roi = rois + r * 5;
    const int   b  = (int)roi[0];
    const float x1 = roi[1] * SCALE;
    const float y1 = roi[2] * SCALE;
    const float x2 = roi[3] * SCALE;
    const float y2 = roi[4] * SCALE;

    const float roi_w = fmaxf(x2 - x1, 0.0f);
    const float roi_h = fmaxf(y2 - y1, 0.0f);
    const float bin_w = roi_w / (float)PW;
    const float bin_h = roi_h / (float)PH;
    const float area  = bin_w * bin_h;
    const float inv_area = (area > 0.0f) ? (1.0f / area) : 0.0f;

    const float* fb = featT + (size_t)b * FH * FW * CH + (size_t)(cbase + 2 * c2);

    for (int kb = 0; kb < 13; ++kb) {
        const int bin = kb * 4 + bq;    // wave-uniform
        if (bin < NBINS) {
            const int ph = bin / PW;
            const int pw = bin - ph * PW;
            const float xa = x1 + pw * bin_w;
            const float xb = xa + bin_w;
            const float ya = y1 + ph * bin_h;
            const float yb = ya + bin_h;

            const int i0 = max(0, (int)floorf(xa) - 1);
            const int i1 = min(FW - 1, (int)floorf(xb) + 1);
            const int j0 = max(0, (int)floorf(ya) - 1);
            const int j1 = min(FH - 1, (int)floorf(yb) + 1);

            float wx[8];
#pragma unroll
            for (int k = 0; k < 8; ++k) {
                const int i = i0 + k;
                wx[k] = (i <= i1) ? (hat_int(xb, (float)i) - hat_int(xa, (float)i)) : 0.0f;
            }

            float accx = 0.0f, accy = 0.0f;
            for (int j = j0; j <= j1; ++j) {
                const float wy = hat_int(yb, (float)j) - hat_int(ya, (float)j);
                const float* frow = fb + (size_t)(j * FW) * CH;
#pragma unroll
                for (int k = 0; k < 8; ++k) {
                    const int i = i0 + k;
                    if (i <= i1) {
                        const float2 v = *(const float2*)(frow + (size_t)i * CH);
                        const float w = wy * wx[k];
                        accx += w * v.x;
                        accy += w * v.y;
                    }
                }
            }
            sm[(2 * c2)     * NBINS + bin] = accx * inv_area;
            sm[(2 * c2 + 1) * NBINS + bin] = accy * inv_area;
        }
    }
    __syncthreads();

    // dense write: out[r, cbase:cbase+128, :, :] is 6272 contiguous floats
    float4* dst4 = (float4*)(out + (size_t)r * CH * NBINS + (size_t)cbase * NBINS);
    const float4* sm4 = (const float4*)sm;
    for (int o = threadIdx.x; o < 128 * NBINS / 4; o += 256) {
        dst4[o] = sm4[o];
    }
}

extern "C" void kernel_launch(void* const* d_in, const int* in_sizes, int n_in,
                              void* d_out, int out_size, void* d_ws, size_t ws_size,
                              hipStream_t stream) {
    const float* feat = (const float*)d_in[0];
    const float* rois = (const float*)d_in[1];
    float* out   = (float*)d_out;
    float* featT = (float*)d_ws;   // needs 8*48*48*256*4 = 18.9 MB

    transpose_bchw_bhwc<<<BATCH * FH, 256, 0, stream>>>(feat, featT);
    prroi_pool_kernel<<<dim3(2, RNUM), 256, 0, stream>>>(featT, rois, out);
}

// Round 3
// 171.918 us; speedup vs baseline: 4.1392x; 1.0592x over previous
//
#include <hip/hip_runtime.h>

// PrRoIPool2D forward, MI355X. B=8, C=256, H=W=48, R=300, 7x7 bins, scale=1/16.
// R2: parallelism fixes. Transpose: 1536 blocks (b,h,c-quarter). Pool: 1200
// blocks (c-quarter, roi), lane=channel (stride-49 LDS staging -> no bank
// conflicts), 4 waves/block over bins.

#define PH 7
#define PW 7
#define NBINS 49
#define SCALE 0.0625f
#define CH 256
#define FH 48
#define FW 48
#define RNUM 300
#define BATCH 8
#define CG 64          // channels per pool block

__device__ __forceinline__ float hat_int(float x, float g) {
    float t = x - (g - 1.0f);
    if (t <= 0.0f) return 0.0f;
    if (t <= 1.0f) return 0.5f * t * t;
    if (t <= 2.0f) { float u = 2.0f - t; return 1.0f - 0.5f * u * u; }
    return 1.0f;
}

// ---- Kernel 1: [B,C,H,W] -> [B,H,W,C] -----------------------------------
// One block per (b, h, channel-quarter): 1536 blocks, 12.5 KB LDS.
// Reads: 64 segments x 192 B (coalesced). Writes: 256 B segments, c-fast.
__global__ __launch_bounds__(256)
void transpose_bchw_bhwc(const float* __restrict__ in, float* __restrict__ outT) {
    const int bid = blockIdx.x;          // 0..1535
    const int cg  = bid & 3;             // channel quarter
    const int bh  = bid >> 2;            // 0..383
    const int b   = bh / FH;
    const int h   = bh % FH;
    __shared__ float sm[CG * (FW + 1)];  // stride 49: odd -> conflict-free

    const float* src = in + (size_t)(b * CH + cg * CG) * FH * FW + (size_t)h * FW;
    // load in input order: idx over (c, w), w fast -> 192 B segments
    for (int idx = threadIdx.x; idx < CG * FW; idx += 256) {
        const int c = idx / FW;
        const int w = idx - c * FW;
        sm[c * (FW + 1) + w] = src[(size_t)c * FH * FW + w];
    }
    __syncthreads();
    // store in output order: idx over (w, c), c fast -> 256 B segments
    float* dst = outT + (size_t)bh * FW * CH + cg * CG;
    for (int idx = threadIdx.x; idx < CG * FW; idx += 256) {
        const int w = idx >> 6;          // 64 c per w
        const int c = idx & 63;
        dst[(size_t)w * CH + c] = sm[c * (FW + 1) + w];
    }
}

// ---- Kernel 2: pooling ---------------------------------------------------
// grid (4, 300): blockIdx.x = channel quarter (64 ch), blockIdx.y = roi.
// 256 threads: lane c = tid&63 -> channel, bq = tid>>6 -> bin = kb*4+bq
// (wave-uniform tap loops). Staged in LDS [64][49] (stride 49, conflict-free),
// then one contiguous 12.5 KB float4 burst.
__global__ __launch_bounds__(256)
void prroi_pool_kernel(const float* __restrict__ featT,
                       const float* __restrict__ rois,
                       float* __restrict__ out) {
    const int cg = blockIdx.x;          // 0..3
    const int r  = blockIdx.y;          // 0..299
    const int cbase = cg * CG;
    const int c  = threadIdx.x & 63;    // channel within group
    const int bq = threadIdx.x >> 6;    // 0..3

    __shared__ float sm[CG * NBINS];    // 12544 B

    const float* roi = rois + r * 5;
    const int   b  = (int)roi[0];
    const float x1 = roi[1] * SCALE;
    const float y1 = roi[2] * SCALE;
    const float x2 = roi[3] * SCALE;
    const float y2 = roi[4] * SCALE;

    const float roi_w = fmaxf(x2 - x1, 0.0f);
    const float roi_h = fmaxf(y2 - y1, 0.0f);
    const float bin_w = roi_w / (float)PW;
    const float bin_h = roi_h / (float)PH;
    const float area  = bin_w * bin_h;
    const float inv_area = (area > 0.0f) ? (1.0f / area) : 0.0f;

    const float* fb = featT + (size_t)b * FH * FW * CH + (size_t)(cbase + c);

    for (int kb = 0; kb < 13; ++kb) {
        const int bin = kb * 4 + bq;    // wave-uniform
        if (bin < NBINS) {
            const int ph = bin / PW;
            const int pw = bin - ph * PW;
            const float xa = x1 + pw * bin_w;
            const float xb = xa + bin_w;
            const float ya = y1 + ph * bin_h;
            const float yb = ya + bin_h;

            const int i0 = max(0, (int)floorf(xa) - 1);
            const int i1 = min(FW - 1, (int)floorf(xb) + 1);
            const int j0 = max(0, (int)floorf(ya) - 1);
            const int j1 = min(FH - 1, (int)floorf(yb) + 1);

            float wx[8];
#pragma unroll
            for (int k = 0; k < 8; ++k) {
                const int i = i0 + k;
                wx[k] = (i <= i1) ? (hat_int(xb, (float)i) - hat_int(xa, (float)i)) : 0.0f;
            }

            float acc = 0.0f;
            for (int j = j0; j <= j1; ++j) {
                const float wy = hat_int(yb, (float)j) - hat_int(ya, (float)j);
                const float* frow = fb + (size_t)(j * FW) * CH;
#pragma unroll
                for (int k = 0; k < 8; ++k) {
                    const int i = i0 + k;
                    if (i <= i1) acc += (wy * wx[k]) * frow[(size_t)i * CH];
                }
            }
            sm[c * NBINS + bin] = acc * inv_area;   // stride 49 -> conflict-free
        }
    }
    __syncthreads();

    // dense write: out[r, cbase:cbase+64, :, :] = 3136 contiguous floats
    float4* dst4 = (float4*)(out + (size_t)r * CH * NBINS + (size_t)cbase * NBINS);
    const float4* sm4 = (const float4*)sm;
    for (int o = threadIdx.x; o < CG * NBINS / 4; o += 256) {
        dst4[o] = sm4[o];
    }
}

extern "C" void kernel_launch(void* const* d_in, const int* in_sizes, int n_in,
                              void* d_out, int out_size, void* d_ws, size_t ws_size,
                              hipStream_t stream) {
    const float* feat = (const float*)d_in[0];
    const float* rois = (const float*)d_in[1];
    float* out   = (float*)d_out;
    float* featT = (float*)d_ws;   // 8*48*48*256*4 = 18.9 MB

    transpose_bchw_bhwc<<<BATCH * FH * 4, 256, 0, stream>>>(feat, featT);
    prroi_pool_kernel<<<dim3(4, RNUM), 256, 0, stream>>>(featT, rois, out);
}

// Round 4
// 140.139 us; speedup vs baseline: 5.0779x; 1.2268x over previous
//
#include <hip/hip_runtime.h>

// PrRoIPool2D forward, MI355X. B=8, C=256, H=W=48, R=300, 7x7 bins, scale=1/16.
// R3: latency attack. Pool: lane=float4 (4 channels), 1 KB/wave per tap, ~81
// loads/wave (was 325), direct register->global stores (no LDS). Transpose:
// LDS-free, float4 reads + L2-merged scatter stores.

#define PH 7
#define PW 7
#define NBINS 49
#define SCALE 0.0625f
#define CH 256
#define FH 48
#define FW 48
#define RNUM 300
#define BATCH 8

__device__ __forceinline__ float hat_int(float x, float g) {
    float t = x - (g - 1.0f);
    if (t <= 0.0f) return 0.0f;
    if (t <= 1.0f) return 0.5f * t * t;
    if (t <= 2.0f) { float u = 2.0f - t; return 1.0f - 0.5f * u * u; }
    return 1.0f;
}

// ---- Kernel 1: [B,C,H,W] -> [B,H,W,C], LDS-free -------------------------
// Block = (b, h, c-half): reads float4 along w (coalesced, 6 x 192 B segments
// per wave-instr); writes 4 scalars stride-1KB. All scatter stays inside the
// block's 24 KB output slab -> merged to full lines in this XCD's L2.
__global__ __launch_bounds__(256)
void transpose_bchw_bhwc(const float* __restrict__ in, float* __restrict__ outT) {
    const int half = blockIdx.x & 1;
    const int bh   = blockIdx.x >> 1;     // 0..383
    const int b    = bh / FH;
    const int h    = bh % FH;

    // 128 channels x 12 float4 = 1536 items, 6 per thread
    for (int idx = threadIdx.x; idx < 128 * 12; idx += 256) {
        const int c  = half * 128 + idx / 12;
        const int w4 = idx % 12;
        const float4 v = *(const float4*)(in + ((size_t)(b * CH + c) * FH + h) * FW + w4 * 4);
        float* dst = outT + ((size_t)(b * FH + h) * FW + w4 * 4) * CH + c;
        dst[0 * CH] = v.x;
        dst[1 * CH] = v.y;
        dst[2 * CH] = v.z;
        dst[3 * CH] = v.w;
    }
}

// ---- Kernel 2: pooling ---------------------------------------------------
// grid (4, 300): blockIdx.x = bin-quarter q (bins q*13 .. min(49,q*13+13)),
// blockIdx.y = roi. 256 threads: lane c4 = tid&63 -> channels 4*c4..4*c4+3
// (float4 taps, 1 KB/wave); wave w = tid>>6 handles local bins w, w+4, w+8,
// w+12 (wave-uniform -> no divergence). Direct stores from registers.
__global__ __launch_bounds__(256)
void prroi_pool_kernel(const float* __restrict__ featT,
                       const float* __restrict__ rois,
                       float* __restrict__ out) {
    const int q  = blockIdx.x;          // 0..3
    const int r  = blockIdx.y;          // 0..299
    const int c4 = threadIdx.x & 63;    // float4 channel group
    const int wv = threadIdx.x >> 6;    // 0..3

    const int bin0 = q * 13;
    const int nb   = min(13, NBINS - bin0);   // 13,13,13,10

    const float* roi = rois + r * 5;
    const int   b  = (int)roi[0];
    const float x1 = roi[1] * SCALE;
    const float y1 = roi[2] * SCALE;
    const float x2 = roi[3] * SCALE;
    const float y2 = roi[4] * SCALE;

    const float roi_w = fmaxf(x2 - x1, 0.0f);
    const float roi_h = fmaxf(y2 - y1, 0.0f);
    const float bin_w = roi_w / (float)PW;
    const float bin_h = roi_h / (float)PH;
    const float area  = bin_w * bin_h;
    const float inv_area = (area > 0.0f) ? (1.0f / area) : 0.0f;

    const float* fb = featT + (size_t)b * FH * FW * CH + 4 * c4;
    float* outr = out + (size_t)r * CH * NBINS + 4 * c4 * NBINS;

    for (int k = 0; k < 4; ++k) {
        const int bl = 4 * k + wv;      // wave-uniform local bin
        if (bl >= nb) break;
        const int bin = bin0 + bl;
        const int ph = bin / PW;
        const int pw = bin - ph * PW;

        const float xa = x1 + pw * bin_w;
        const float xb = xa + bin_w;
        const float ya = y1 + ph * bin_h;
        const float yb = ya + bin_h;

        const int i0 = max(0, (int)floorf(xa) - 1);
        const int i1 = min(FW - 1, (int)floorf(xb) + 1);
        const int j0 = max(0, (int)floorf(ya) - 1);
        const int j1 = min(FH - 1, (int)floorf(yb) + 1);

        float wx[8];
#pragma unroll
        for (int t = 0; t < 8; ++t) {
            const int i = i0 + t;
            wx[t] = (i <= i1) ? (hat_int(xb, (float)i) - hat_int(xa, (float)i)) : 0.0f;
        }

        float ax = 0.0f, ay = 0.0f, az = 0.0f, aw = 0.0f;
        for (int j = j0; j <= j1; ++j) {
            const float wy = hat_int(yb, (float)j) - hat_int(ya, (float)j);
            const float* frow = fb + (size_t)(j * FW) * CH;
#pragma unroll
            for (int t = 0; t < 8; ++t) {
                const int i = i0 + t;
                if (i <= i1) {
                    const float4 v = *(const float4*)(frow + (size_t)i * CH);
                    const float wgt = wy * wx[t];
                    ax += wgt * v.x;
                    ay += wgt * v.y;
                    az += wgt * v.z;
                    aw += wgt * v.w;
                }
            }
        }
        outr[0 * NBINS + bin] = ax * inv_area;
        outr[1 * NBINS + bin] = ay * inv_area;
        outr[2 * NBINS + bin] = az * inv_area;
        outr[3 * NBINS + bin] = aw * inv_area;
    }
}

extern "C" void kernel_launch(void* const* d_in, const int* in_sizes, int n_in,
                              void* d_out, int out_size, void* d_ws, size_t ws_size,
                              hipStream_t stream) {
    const float* feat = (const float*)d_in[0];
    const float* rois = (const float*)d_in[1];
    float* out   = (float*)d_out;
    float* featT = (float*)d_ws;   // 8*48*48*256*4 = 18.9 MB

    transpose_bchw_bhwc<<<BATCH * FH * 2, 256, 0, stream>>>(feat, featT);
    prroi_pool_kernel<<<dim3(4, RNUM), 256, 0, stream>>>(featT, rois, out);
}

// Round 5
// 106.316 us; speedup vs baseline: 6.6933x; 1.3181x over previous
//
#include <hip/hip_runtime.h>

// PrRoIPool2D forward, MI355X. B=8, C=256, H=W=48, R=300, 7x7 bins, scale=1/16.
// R4: single fused kernel, no transpose. Block = (roi, 8-channel group).
//  P1: stage the ROI's 8-channel patch (<=23 rows x 28 floats) in LDS via
//      float4 loads along w (BCHW rows are contiguous -> coalesced enough).
//  P2: 14 threads precompute per-bin hat weights (wx ~ pw only, wy ~ ph only).
//  P3: lane=bin, wave=channel: exact <=6x6 tap windows from LDS, contiguous
//      output stores. 21 KB LDS -> 7 blocks/CU (28 waves/CU).

#define PH 7
#define PW 7
#define NBINS 49
#define SCALE 0.0625f
#define CH 256
#define FH 48
#define FW 48
#define RNUM 300
#define CB 8                 // channels per block
#define MAXJ 23              // max patch rows (roi_h <= 20 fpx -> span <= 23)
#define ROWF 28              // floats per patch row (<=26 needed, round up)

__device__ __forceinline__ float hat_int(float x, float g) {
    float t = x - (g - 1.0f);
    if (t <= 0.0f) return 0.0f;
    if (t <= 1.0f) return 0.5f * t * t;
    if (t <= 2.0f) { float u = 2.0f - t; return 1.0f - 0.5f * u * u; }
    return 1.0f;
}

__global__ __launch_bounds__(256)
void prroi_fused(const float* __restrict__ feat,
                 const float* __restrict__ rois,
                 float* __restrict__ out) {
    const int cblk = blockIdx.x;        // 0..31
    const int r    = blockIdx.y;        // 0..299
    const int c0   = cblk * CB;
    const int tid  = threadIdx.x;

    __shared__ float patch[CB * MAXJ * ROWF];   // 20608 B
    __shared__ float s_wy[PH][6];
    __shared__ float s_wx[PW][6];
    __shared__ int   s_jb[PH], s_jc[PH];        // bin j start (patch-rel), count
    __shared__ int   s_ib[PW], s_ic[PW];        // bin i start (patch-rel), count

    // ---- uniform ROI params ----
    const float* roi = rois + r * 5;
    const int   b  = (int)roi[0];
    const float x1 = roi[1] * SCALE, y1 = roi[2] * SCALE;
    const float x2 = roi[3] * SCALE, y2 = roi[4] * SCALE;
    const float roi_w = fmaxf(x2 - x1, 0.0f), roi_h = fmaxf(y2 - y1, 0.0f);
    const float bin_w = roi_w / (float)PW, bin_h = roi_h / (float)PH;
    const float area = bin_w * bin_h;
    const float inv_area = (area > 0.0f) ? (1.0f / area) : 0.0f;

    // patch bounds (use min/max so degenerate rois still stay in-patch)
    const float ylo = fminf(y1, y2), yhi = fmaxf(y1, y2);
    const float xlo = fminf(x1, x2), xhi = fmaxf(x1, x2);
    const int j0  = max(0, (int)floorf(ylo) - 1);
    const int j1  = min(FH - 1, (int)floorf(yhi) + 1);
    const int i0  = max(0, (int)floorf(xlo) - 1);
    const int i1  = min(FW - 1, (int)floorf(xhi) + 1);
    const int i0a = i0 & ~3;                     // float4-aligned start
    const int jspan = j1 - j0 + 1;               // <= 23
    const int ni4   = ((i1 - i0a) >> 2) + 1;     // <= 7 float4 per row

    // ---- P2: per-bin weights (14 threads) ----
    if (tid < PH + PW) {
        if (tid < PH) {
            const int ph = tid;
            const float ya = y1 + ph * bin_h, yb = ya + bin_h;
            int jb0 = max(0, (int)floorf(ya) - 1);
            int jb1 = min(FH - 1, (int)floorf(yb) + 1);
            jb0 = max(jb0, j0); jb1 = min(jb1, j1);      // clamp into patch
            s_jb[ph] = jb0 - j0;
            s_jc[ph] = jb1 - jb0 + 1;
#pragma unroll
            for (int k = 0; k < 6; ++k) {
                const float g = (float)(jb0 + k);
                s_wy[ph][k] = hat_int(yb, g) - hat_int(ya, g);
            }
        } else {
            const int pw = tid - PH;
            const float xa = x1 + pw * bin_w, xb = xa + bin_w;
            int ib0 = max(0, (int)floorf(xa) - 1);
            int ib1 = min(FW - 1, (int)floorf(xb) + 1);
            ib0 = max(ib0, i0); ib1 = min(ib1, i1);
            s_ib[pw] = ib0 - i0a;
            s_ic[pw] = ib1 - ib0 + 1;
#pragma unroll
            for (int k = 0; k < 6; ++k) {
                const float g = (float)(ib0 + k);
                s_wx[pw][k] = hat_int(xb, g) - hat_int(xa, g);
            }
        }
    }

    // ---- P1: stage patch into LDS (float4, always in-bounds: start%4==0 -> <=44) ----
    const int per_c  = jspan * ni4;              // <= 161
    const int total  = CB * per_c;               // <= 1288
    const float* fb  = feat + (size_t)(b * CH + c0) * FH * FW;
    for (int idx = tid; idx < total; idx += 256) {
        const int c  = idx / per_c;
        const int rj = idx - c * per_c;
        const int j  = rj / ni4;
        const int i4 = rj - j * ni4;
        const float4 v = *(const float4*)(fb + ((size_t)c * FH + (j0 + j)) * FW + i0a + 4 * i4);
        *(float4*)(&patch[(c * MAXJ + j) * ROWF + 4 * i4]) = v;
    }
    __syncthreads();

    // ---- P3: compute. lane = bin (49 of 64), wave = channel, 2 passes ----
    const int lane = tid & 63;
    const int wv   = tid >> 6;
    if (lane < NBINS) {
        const int ph = lane / PW;
        const int pw = lane - ph * PW;
        const int jb = s_jb[ph], jc = s_jc[ph];
        const int ib = s_ib[pw], ic = s_ic[pw];
#pragma unroll
        for (int p = 0; p < 2; ++p) {
            const int c = p * 4 + wv;
            const float* pc = &patch[(c * MAXJ + jb) * ROWF + ib];
            float acc = 0.0f;
            for (int jj = 0; jj < jc; ++jj) {
                const float wy = s_wy[ph][jj];
                const float* prow = pc + jj * ROWF;
                float rs = 0.0f;
                for (int ii = 0; ii < ic; ++ii)
                    rs += s_wx[pw][ii] * prow[ii];
                acc += wy * rs;
            }
            out[((size_t)r * CH + c0 + c) * NBINS + lane] = acc * inv_area;
        }
    }
}

extern "C" void kernel_launch(void* const* d_in, const int* in_sizes, int n_in,
                              void* d_out, int out_size, void* d_ws, size_t ws_size,
                              hipStream_t stream) {
    const float* feat = (const float*)d_in[0];
    const float* rois = (const float*)d_in[1];
    float* out = (float*)d_out;

    prroi_fused<<<dim3(CH / CB, RNUM), 256, 0, stream>>>(feat, rois, out);
}

// Round 6
// 99.144 us; speedup vs baseline: 7.1776x; 1.0723x over previous
//
#include <hip/hip_runtime.h>

// PrRoIPool2D forward, MI355X. B=8, C=256, H=W=48, R=300, 7x7 bins, scale=1/16.
// R6: LDS-vectorized fused kernel. Patch stored channel-fast [j][i][c16] so
// P3 reads ds_read_b128 (4 channels/MAC-group) with weights in registers;
// P1 does an in-register 4x4 transpose (4 global float4 -> 4 LDS b128).
// CB=16 -> 4800 blocks, 41.7 KB LDS, 3 blocks/CU.

#define PH 7
#define PW 7
#define NBINS 49
#define SCALE 0.0625f
#define CH 256
#define FH 48
#define FW 48
#define RNUM 300
#define CB 16                // channels per block
#define MAXJ 23              // max patch rows
#define ROWF 28              // patch row width (floats, covers ni4*4 <= 28)

__device__ __forceinline__ float hat_int(float x, float g) {
    float t = x - (g - 1.0f);
    if (t <= 0.0f) return 0.0f;
    if (t <= 1.0f) return 0.5f * t * t;
    if (t <= 2.0f) { float u = 2.0f - t; return 1.0f - 0.5f * u * u; }
    return 1.0f;
}

__global__ __launch_bounds__(256)
void prroi_fused(const float* __restrict__ feat,
                 const float* __restrict__ rois,
                 float* __restrict__ out) {
    const int cblk = blockIdx.x;        // 0..15
    const int r    = blockIdx.y;        // 0..299
    const int c0   = cblk * CB;
    const int tid  = threadIdx.x;

    __shared__ float patch[MAXJ * ROWF * CB];   // [j][i][c] 41216 B
    __shared__ float s_wy[PH][6];
    __shared__ float s_wx[PW][6];
    __shared__ int   s_jb[PH], s_jc[PH];        // window start (patch row), count
    __shared__ int   s_ib[PW], s_ic[PW];        // window start (patch col), count

    // ---- uniform ROI params ----
    const float* roi = rois + r * 5;
    const int   b  = (int)roi[0];
    const float x1 = roi[1] * SCALE, y1 = roi[2] * SCALE;
    const float x2 = roi[3] * SCALE, y2 = roi[4] * SCALE;
    const float roi_w = fmaxf(x2 - x1, 0.0f), roi_h = fmaxf(y2 - y1, 0.0f);
    const float bin_w = roi_w / (float)PW, bin_h = roi_h / (float)PH;
    const float area = bin_w * bin_h;
    const float inv_area = (area > 0.0f) ? (1.0f / area) : 0.0f;

    const float ylo = fminf(y1, y2), yhi = fmaxf(y1, y2);
    const float xlo = fminf(x1, x2), xhi = fmaxf(x1, x2);
    const int j0  = max(0, (int)floorf(ylo) - 1);
    const int j1  = min(FH - 1, (int)floorf(yhi) + 1);
    const int i0  = max(0, (int)floorf(xlo) - 1);
    const int i1  = min(FW - 1, (int)floorf(xhi) + 1);
    const int i0a = i0 & ~3;
    const int jspan = j1 - j0 + 1;               // <= 23
    const int ni4   = ((i1 - i0a) >> 2) + 1;     // <= 7

    // ---- P2: per-bin windows + weights (14 threads) ----
    if (tid < PH + PW) {
        if (tid < PH) {
            const int ph = tid;
            const float ya = y1 + ph * bin_h, yb = ya + bin_h;
            int jb0 = max(0, (int)floorf(ya) - 1);
            int jb1 = min(FH - 1, (int)floorf(yb) + 1);
            jb0 = max(jb0, j0); jb1 = min(jb1, j1);
            s_jb[ph] = jb0 - j0;
            s_jc[ph] = jb1 - jb0 + 1;            // <= 6
#pragma unroll
            for (int k = 0; k < 6; ++k) {
                const float g = (float)(jb0 + k);
                s_wy[ph][k] = hat_int(yb, g) - hat_int(ya, g);
            }
        } else {
            const int pw = tid - PH;
            const float xa = x1 + pw * bin_w, xb = xa + bin_w;
            int ib0 = max(0, (int)floorf(xa) - 1);
            int ib1 = min(FW - 1, (int)floorf(xb) + 1);
            ib0 = max(ib0, i0); ib1 = min(ib1, i1);
            s_ib[pw] = ib0 - i0a;
            s_ic[pw] = ib1 - ib0 + 1;            // <= 6
#pragma unroll
            for (int k = 0; k < 6; ++k) {
                const float g = (float)(ib0 + k);
                s_wx[pw][k] = hat_int(xb, g) - hat_int(xa, g);
            }
        }
    }

    // ---- P1: stage patch, channel-fast, via in-register 4x4 transpose ----
    // fixed decomposition: unit u -> (q, j, i4) over 4 x 23 x 7 = 644,
    // guarded by runtime (jspan, ni4). Compile-time divisors only.
    const float* fb = feat + (size_t)(b * CH + c0) * FH * FW;
    for (int u = tid; u < 4 * MAXJ * 7; u += 256) {
        const int q   = u / (MAXJ * 7);          // channel quad 0..3
        const int rem = u - q * (MAXJ * 7);
        const int j   = rem / 7;
        const int i4  = rem - j * 7;
        if (j < jspan && i4 < ni4) {
            int ig = i0a + 4 * i4;
            if (ig > FW - 4) ig = FW - 4;        // clamp: avoid OOB read at row tail
            const float* src = fb + ((size_t)(4 * q) * FH + (j0 + j)) * FW + ig;
            const float4 v0 = *(const float4*)(src);
            const float4 v1 = *(const float4*)(src + FH * FW);
            const float4 v2 = *(const float4*)(src + 2 * FH * FW);
            const float4 v3 = *(const float4*)(src + 3 * FH * FW);
            float* dst = &patch[((size_t)j * ROWF + (ig - i0a)) * CB + 4 * q];
            *(float4*)(dst + 0 * CB) = make_float4(v0.x, v1.x, v2.x, v3.x);
            *(float4*)(dst + 1 * CB) = make_float4(v0.y, v1.y, v2.y, v3.y);
            *(float4*)(dst + 2 * CB) = make_float4(v0.z, v1.z, v2.z, v3.z);
            *(float4*)(dst + 3 * CB) = make_float4(v0.w, v1.w, v2.w, v3.w);
        }
    }
    __syncthreads();

    // ---- P3: thread = (bin, channel-quad). float4 taps, weights in regs ----
    const int bin = tid >> 2;                    // 0..63 (49 active)
    const int q   = tid & 3;
    if (bin < NBINS) {
        const int ph = bin / PW;
        const int pw = bin - ph * PW;
        const int jb = s_jb[ph], jc = s_jc[ph];
        const int ib = s_ib[pw], ic = s_ic[pw];
        float wy[6], wx[6];
#pragma unroll
        for (int k = 0; k < 6; ++k) { wy[k] = s_wy[ph][k]; wx[k] = s_wx[pw][k]; }

        float ax = 0.0f, ay = 0.0f, az = 0.0f, aw = 0.0f;
        const float* pc = &patch[((size_t)jb * ROWF + ib) * CB + 4 * q];
        for (int jj = 0; jj < jc; ++jj) {
            const float* prow = pc + (size_t)jj * (ROWF * CB);
            const float wyj = wy[jj];
#pragma unroll
            for (int ii = 0; ii < 6; ++ii) {
                if (ii < ic) {
                    const float w = wyj * wx[ii];
                    const float4 v = *(const float4*)(prow + ii * CB);
                    ax += w * v.x;
                    ay += w * v.y;
                    az += w * v.z;
                    aw += w * v.w;
                }
            }
        }
        float* o = out + ((size_t)r * CH + c0 + 4 * q) * NBINS + bin;
        o[0 * NBINS] = ax * inv_area;
        o[1 * NBINS] = ay * inv_area;
        o[2 * NBINS] = az * inv_area;
        o[3 * NBINS] = aw * inv_area;
    }
}

extern "C" void kernel_launch(void* const* d_in, const int* in_sizes, int n_in,
                              void* d_out, int out_size, void* d_ws, size_t ws_size,
                              hipStream_t stream) {
    const float* feat = (const float*)d_in[0];
    const float* rois = (const float*)d_in[1];
    float* out = (float*)d_out;

    prroi_fused<<<dim3(CH / CB, RNUM), 256, 0, stream>>>(feat, rois, out);
}

// Round 7
// 93.752 us; speedup vs baseline: 7.5903x; 1.0575x over previous
//
#include <hip/hip_runtime.h>

// PrRoIPool2D forward, MI355X. B=8, C=256, H=W=48, R=300, 7x7 bins, scale=1/16.
// R7: separable uniform-window fused kernel.
//  P1: stage exact patch rectangle [J0..J0+JROWS-1] x [I0..I0+4*NI4-1] in LDS,
//      channel-fast [j][i][c16], via in-register 4x4 transpose.
//  P2: per-bin 6-tap windows with base clamped into the patch; hat-integral
//      weights are naturally zero outside true support -> NO guards/divergence.
//  PA: rs[pw][j][c16] = sum_i wx[pw][i] * patch[j][i][c]  (shared across ph)
//  PB: out[ph][pw][c] = inv_area * sum_j wy[ph][j] * rs[pw][j][c]
// LDS 51.9 KB -> 3 blocks/CU. 4800 blocks.

#define PH 7
#define PW 7
#define NBINS 49
#define SCALE 0.0625f
#define CH 256
#define FH 48
#define FW 48
#define RNUM 300
#define CB 16                // channels per block
#define MAXJ 23              // max patch rows
#define ROWF 28              // max patch row width (floats)

__device__ __forceinline__ float hat_int(float x, float g) {
    float t = x - (g - 1.0f);
    if (t <= 0.0f) return 0.0f;
    if (t <= 1.0f) return 0.5f * t * t;
    if (t <= 2.0f) { float u = 2.0f - t; return 1.0f - 0.5f * u * u; }
    return 1.0f;
}

__global__ __launch_bounds__(256)
void prroi_fused(const float* __restrict__ feat,
                 const float* __restrict__ rois,
                 float* __restrict__ out) {
    const int cblk = blockIdx.x;        // 0..15
    const int r    = blockIdx.y;        // 0..299
    const int c0   = cblk * CB;
    const int tid  = threadIdx.x;

    __shared__ float patch[MAXJ * ROWF * CB];   // [j][i][c16] 41216 B
    __shared__ float rs[PW * MAXJ * CB];        // [pw][j][c16] 10304 B
    __shared__ float s_wy[PH][6];
    __shared__ float s_wx[PW][6];
    __shared__ int   s_bj[PH];                  // window base (patch-rel rows)
    __shared__ int   s_bi[PW];                  // window base (patch-rel cols)

    // ---- uniform ROI params ----
    const float* roi = rois + r * 5;
    const int   b  = (int)roi[0];
    const float x1 = roi[1] * SCALE, y1 = roi[2] * SCALE;
    const float x2 = roi[3] * SCALE, y2 = roi[4] * SCALE;
    const float roi_w = fmaxf(x2 - x1, 0.0f), roi_h = fmaxf(y2 - y1, 0.0f);
    const float bin_w = roi_w / (float)PW, bin_h = roi_h / (float)PH;
    const float area = bin_w * bin_h;
    const float inv_area = (area > 0.0f) ? (1.0f / area) : 0.0f;

    const float ylo = fminf(y1, y2), yhi = fmaxf(y1, y2);
    const float xlo = fminf(x1, x2), xhi = fmaxf(x1, x2);
    const int j1 = min(FH - 1, (int)floorf(yhi) + 1);
    const int i1 = min(FW - 1, (int)floorf(xhi) + 1);
    // patch origin: row base clamped so >=6 rows always loadable; col base
    // float4-aligned with >=8 cols loadable.
    const int J0 = min(max(0, (int)floorf(ylo) - 1), FH - 6);
    const int I0 = min(max(0, (int)floorf(xlo) - 1) & ~3, FW - 8);
    const int JROWS = min(FH - J0, max(j1 - J0 + 1, 6));        // 6..23
    int NI4 = min(((i1 - I0) >> 2) + 1, (FW - I0) >> 2);        // never OOB
    NI4 = max(NI4, 2);                                           // 2..7

    // ---- P2: per-bin 6-tap windows + weights (14 threads) ----
    if (tid < PH + PW) {
        if (tid < PH) {
            const int ph = tid;
            const float ya = y1 + ph * bin_h, yb = ya + bin_h;
            const int base = min(max((int)floorf(ya) - 1, J0), J0 + JROWS - 6);
            s_bj[ph] = base - J0;
#pragma unroll
            for (int k = 0; k < 6; ++k) {
                const float g = (float)(base + k);
                s_wy[ph][k] = hat_int(yb, g) - hat_int(ya, g);  // 0 outside support
            }
        } else {
            const int pw = tid - PH;
            const float xa = x1 + pw * bin_w, xb = xa + bin_w;
            const int base = min(max((int)floorf(xa) - 1, I0), I0 + 4 * NI4 - 6);
            s_bi[pw] = base - I0;
#pragma unroll
            for (int k = 0; k < 6; ++k) {
                const float g = (float)(base + k);
                s_wx[pw][k] = hat_int(xb, g) - hat_int(xa, g);  // 0 outside support
            }
        }
    }

    // ---- P1: stage patch rectangle, channel-fast, 4x4 register transpose ----
    const float* fb = feat + (size_t)(b * CH + c0) * FH * FW;
    for (int u = tid; u < 4 * MAXJ * 7; u += 256) {
        const int q   = u / (MAXJ * 7);          // channel quad 0..3
        const int rem = u - q * (MAXJ * 7);
        const int j   = rem / 7;
        const int i4  = rem - j * 7;
        if (j < JROWS && i4 < NI4) {
            const int ig = I0 + 4 * i4;          // <= FW-4 by construction
            const float* src = fb + ((size_t)(4 * q) * FH + (J0 + j)) * FW + ig;
            const float4 v0 = *(const float4*)(src);
            const float4 v1 = *(const float4*)(src + FH * FW);
            const float4 v2 = *(const float4*)(src + 2 * FH * FW);
            const float4 v3 = *(const float4*)(src + 3 * FH * FW);
            float* dst = &patch[((size_t)j * ROWF + 4 * i4) * CB + 4 * q];
            *(float4*)(dst + 0 * CB) = make_float4(v0.x, v1.x, v2.x, v3.x);
            *(float4*)(dst + 1 * CB) = make_float4(v0.y, v1.y, v2.y, v3.y);
            *(float4*)(dst + 2 * CB) = make_float4(v0.z, v1.z, v2.z, v3.z);
            *(float4*)(dst + 3 * CB) = make_float4(v0.w, v1.w, v2.w, v3.w);
        }
    }
    __syncthreads();

    // ---- PA: row sums rs[pw][j][c16], uniform 6 taps, no divergence ----
    for (int u = tid; u < JROWS * 28; u += 256) {
        const int j   = u / 28;
        const int rem = u - j * 28;
        const int pw  = rem >> 2;                // 0..6
        const int q   = rem & 3;                 // channel quad
        const int bi  = s_bi[pw];
        const float* base = &patch[((size_t)j * ROWF + bi) * CB + 4 * q];
        float ax = 0.0f, ay = 0.0f, az = 0.0f, aw = 0.0f;
#pragma unroll
        for (int ii = 0; ii < 6; ++ii) {
            const float w = s_wx[pw][ii];
            const float4 v = *(const float4*)(base + ii * CB);
            ax += w * v.x; ay += w * v.y; az += w * v.z; aw += w * v.w;
        }
        *(float4*)(&rs[((size_t)pw * MAXJ + j) * CB + 4 * q]) =
            make_float4(ax, ay, az, aw);
    }
    __syncthreads();

    // ---- PB: combine over rows, uniform 6 taps; contiguous-ish stores ----
    const int bin = tid & 63;                    // 49 active per wave (balanced)
    const int q   = tid >> 6;                    // 0..3
    if (bin < NBINS) {
        const int ph = bin / PW;
        const int pw = bin - ph * PW;
        const int bj = s_bj[ph];
        const float* rbase = &rs[((size_t)pw * MAXJ + bj) * CB + 4 * q];
        float ax = 0.0f, ay = 0.0f, az = 0.0f, aw = 0.0f;
#pragma unroll
        for (int jj = 0; jj < 6; ++jj) {
            const float w = s_wy[ph][jj];
            const float4 v = *(const float4*)(rbase + jj * CB);
            ax += w * v.x; ay += w * v.y; az += w * v.z; aw += w * v.w;
        }
        float* o = out + ((size_t)r * CH + c0 + 4 * q) * NBINS + bin;
        o[0 * NBINS] = ax * inv_area;
        o[1 * NBINS] = ay * inv_area;
        o[2 * NBINS] = az * inv_area;
        o[3 * NBINS] = aw * inv_area;
    }
}

extern "C" void kernel_launch(void* const* d_in, const int* in_sizes, int n_in,
                              void* d_out, int out_size, void* d_ws, size_t ws_size,
                              hipStream_t stream) {
    const float* feat = (const float*)d_in[0];
    const float* rois = (const float*)d_in[1];
    float* out = (float*)d_out;

    prroi_fused<<<dim3(CH / CB, RNUM), 256, 0, stream>>>(feat, rois, out);
}

// Round 8
// 91.791 us; speedup vs baseline: 7.7525x; 1.0214x over previous
//
#include <hip/hip_runtime.h>

// PrRoIPool2D forward, MI355X. B=8, C=256, H=W=48, R=300, 7x7 bins, scale=1/16.
// R8: R7's separable uniform-window kernel at CB=8 for 2x occupancy.
// LDS 26.2 KB -> 6 blocks/CU (24 waves/CU), 9600 blocks.
//  P1: stage patch rectangle channel-fast [j][i][c8] (4x4 register transpose).
//  P2: per-bin clamped 6-tap windows; weights naturally 0 outside support.
//  PA: rs[pw][j][c8] = sum_i wx[pw][i] * patch[j][i][c]   (shared across ph)
//  PB: out = inv_area * sum_j wy[ph][j] * rs[pw][j][c], float2 channel-pairs.

#define PH 7
#define PW 7
#define NBINS 49
#define SCALE 0.0625f
#define CH 256
#define FH 48
#define FW 48
#define RNUM 300
#define CB 8                 // channels per block
#define QN 2                 // channel quads per block
#define MAXJ 23              // max patch rows
#define ROWF 28              // max patch row width (floats)

__device__ __forceinline__ float hat_int(float x, float g) {
    float t = x - (g - 1.0f);
    if (t <= 0.0f) return 0.0f;
    if (t <= 1.0f) return 0.5f * t * t;
    if (t <= 2.0f) { float u = 2.0f - t; return 1.0f - 0.5f * u * u; }
    return 1.0f;
}

__global__ __launch_bounds__(256)
void prroi_fused(const float* __restrict__ feat,
                 const float* __restrict__ rois,
                 float* __restrict__ out) {
    const int cblk = blockIdx.x;        // 0..31
    const int r    = blockIdx.y;        // 0..299
    const int c0   = cblk * CB;
    const int tid  = threadIdx.x;

    __shared__ float patch[MAXJ * ROWF * CB];   // [j][i][c8] 20608 B
    __shared__ float rs[PW * MAXJ * CB];        // [pw][j][c8]  5152 B
    __shared__ float s_wy[PH][6];
    __shared__ float s_wx[PW][6];
    __shared__ int   s_bj[PH];                  // window base (patch-rel rows)
    __shared__ int   s_bi[PW];                  // window base (patch-rel cols)

    // ---- uniform ROI params ----
    const float* roi = rois + r * 5;
    const int   b  = (int)roi[0];
    const float x1 = roi[1] * SCALE, y1 = roi[2] * SCALE;
    const float x2 = roi[3] * SCALE, y2 = roi[4] * SCALE;
    const float roi_w = fmaxf(x2 - x1, 0.0f), roi_h = fmaxf(y2 - y1, 0.0f);
    const float bin_w = roi_w / (float)PW, bin_h = roi_h / (float)PH;
    const float area = bin_w * bin_h;
    const float inv_area = (area > 0.0f) ? (1.0f / area) : 0.0f;

    const float ylo = fminf(y1, y2), yhi = fmaxf(y1, y2);
    const float xlo = fminf(x1, x2), xhi = fmaxf(x1, x2);
    const int j1 = min(FH - 1, (int)floorf(yhi) + 1);
    const int i1 = min(FW - 1, (int)floorf(xhi) + 1);
    const int J0 = min(max(0, (int)floorf(ylo) - 1), FH - 6);
    const int I0 = min(max(0, (int)floorf(xlo) - 1) & ~3, FW - 8);
    const int JROWS = min(FH - J0, max(j1 - J0 + 1, 6));        // 6..23
    int NI4 = min(((i1 - I0) >> 2) + 1, (FW - I0) >> 2);        // never OOB
    NI4 = max(NI4, 2);                                           // 2..7

    // ---- P2: per-bin 6-tap windows + weights (14 threads) ----
    if (tid < PH + PW) {
        if (tid < PH) {
            const int ph = tid;
            const float ya = y1 + ph * bin_h, yb = ya + bin_h;
            const int base = min(max((int)floorf(ya) - 1, J0), J0 + JROWS - 6);
            s_bj[ph] = base - J0;
#pragma unroll
            for (int k = 0; k < 6; ++k) {
                const float g = (float)(base + k);
                s_wy[ph][k] = hat_int(yb, g) - hat_int(ya, g);  // 0 outside support
            }
        } else {
            const int pw = tid - PH;
            const float xa = x1 + pw * bin_w, xb = xa + bin_w;
            const int base = min(max((int)floorf(xa) - 1, I0), I0 + 4 * NI4 - 6);
            s_bi[pw] = base - I0;
#pragma unroll
            for (int k = 0; k < 6; ++k) {
                const float g = (float)(base + k);
                s_wx[pw][k] = hat_int(xb, g) - hat_int(xa, g);  // 0 outside support
            }
        }
    }

    // ---- P1: stage patch rectangle, channel-fast, 4x4 register transpose ----
    const float* fb = feat + (size_t)(b * CH + c0) * FH * FW;
    for (int u = tid; u < QN * MAXJ * 7; u += 256) {   // 322 units
        const int q   = u / (MAXJ * 7);                // channel quad 0..1
        const int rem = u - q * (MAXJ * 7);
        const int j   = rem / 7;
        const int i4  = rem - j * 7;
        if (j < JROWS && i4 < NI4) {
            const int ig = I0 + 4 * i4;                // <= FW-4 by construction
            const float* src = fb + ((size_t)(4 * q) * FH + (J0 + j)) * FW + ig;
            const float4 v0 = *(const float4*)(src);
            const float4 v1 = *(const float4*)(src + FH * FW);
            const float4 v2 = *(const float4*)(src + 2 * FH * FW);
            const float4 v3 = *(const float4*)(src + 3 * FH * FW);
            float* dst = &patch[((size_t)j * ROWF + 4 * i4) * CB + 4 * q];
            *(float4*)(dst + 0 * CB) = make_float4(v0.x, v1.x, v2.x, v3.x);
            *(float4*)(dst + 1 * CB) = make_float4(v0.y, v1.y, v2.y, v3.y);
            *(float4*)(dst + 2 * CB) = make_float4(v0.z, v1.z, v2.z, v3.z);
            *(float4*)(dst + 3 * CB) = make_float4(v0.w, v1.w, v2.w, v3.w);
        }
    }
    __syncthreads();

    // ---- PA: row sums rs[pw][j][c8], uniform 6 taps, no divergence ----
    for (int u = tid; u < JROWS * 14; u += 256) {      // <= 322 units
        const int j   = u / 14;
        const int rem = u - j * 14;
        const int pw  = rem >> 1;                      // 0..6
        const int q   = rem & 1;                       // channel quad
        const int bi  = s_bi[pw];
        const float* base = &patch[((size_t)j * ROWF + bi) * CB + 4 * q];
        float ax = 0.0f, ay = 0.0f, az = 0.0f, aw = 0.0f;
#pragma unroll
        for (int ii = 0; ii < 6; ++ii) {
            const float w = s_wx[pw][ii];
            const float4 v = *(const float4*)(base + ii * CB);
            ax += w * v.x; ay += w * v.y; az += w * v.z; aw += w * v.w;
        }
        *(float4*)(&rs[((size_t)pw * MAXJ + j) * CB + 4 * q]) =
            make_float4(ax, ay, az, aw);
    }
    __syncthreads();

    // ---- PB: combine over rows, float2 channel-pairs; all 4 waves active ----
    const int bin = tid & 63;                          // 49 active per wave
    const int cp  = tid >> 6;                          // channel pair 0..3
    if (bin < NBINS) {
        const int ph = bin / PW;
        const int pw = bin - ph * PW;
        const int bj = s_bj[ph];
        const float* rbase = &rs[((size_t)pw * MAXJ + bj) * CB + 2 * cp];
        float ax = 0.0f, ay = 0.0f;
#pragma unroll
        for (int jj = 0; jj < 6; ++jj) {
            const float w = s_wy[ph][jj];
            const float2 v = *(const float2*)(rbase + jj * CB);
            ax += w * v.x; ay += w * v.y;
        }
        float* o = out + ((size_t)r * CH + c0 + 2 * cp) * NBINS + bin;
        o[0]     = ax * inv_area;
        o[NBINS] = ay * inv_area;
    }
}

extern "C" void kernel_launch(void* const* d_in, const int* in_sizes, int n_in,
                              void* d_out, int out_size, void* d_ws, size_t ws_size,
                              hipStream_t stream) {
    const float* feat = (const float*)d_in[0];
    const float* rois = (const float*)d_in[1];
    float* out = (float*)d_out;

    prroi_fused<<<dim3(CH / CB, RNUM), 256, 0, stream>>>(feat, rois, out);
}